// Round 11
// baseline (73.763 us; speedup 1.0000x reference)
//
#include <hip/hip_runtime.h>
#include <math.h>

// Problem constants (from reference):
//   vol: (B=1, C=1, W=96, H=96, D=64) float32, row-major -> vol[(x*96+y)*64+z]
//   out: (B,C,U=96,A=90,V=64) float32 -> out[(u*90+a)*64+v]
namespace {
constexpr int NA = 90, NU = 96, NV = 64, NW = 96, NH = 96, ND = 64;
constexpr int NRAY   = NA * NU;      // 8640
constexpr int NVOX   = NW * NH * ND; // 589824
constexpr int NENT   = 256;          // entries per ray (4 rounds x 64 lanes)
constexpr int CNTMAX = 224;          // gather cap, multiple of 32
constexpr int TILE   = 8;            // rays per block = waves per block
constexpr int NBLK   = NRAY / TILE;  // 1080 blocks (~4.2/CU)
typedef _Float16 f16_t;
}

// R11: f16 volume. R10 post-mortem: kernel ~25us (below the 40.5us poison
// fills in top-5), gather-dominated. Floor = L1 return path: 1.18M entries
// x 256B/row = 302MB L1->VGPR (~11us at 64B/cyc/CU) + cold misses (the 268MB
// ws-poison sweeps L2/L3 every iter). FMA issue ~1us. Lever: bytes/entry.
// Prologue converts vol to f16 (1.18MB in d_ws, rebuilt every call since ws
// is re-poisoned); rows become 128B -> one dwordx4 per lane covers EIGHT
// rows per wave-instr (2x fewer VMEM instrs, 2x fewer bytes). Error budget:
// f16 adds ~2^-11/term, ~137-term sums -> ~0.02 absmax vs 1.18 threshold.
__global__ __launch_bounds__(256)
void vol_to_f16(const float* __restrict__ vol, f16_t* __restrict__ v16)
{
    const int idx = (blockIdx.x * 256 + threadIdx.x) * 4;  // NVOX/4 threads exact
    const float4 f = *(const float4*)(vol + idx);
    f16_t h[4];
    h[0] = (f16_t)f.x; h[1] = (f16_t)f.y; h[2] = (f16_t)f.z; h[3] = (f16_t)f.w;
    *(ushort4*)(v16 + idx) = *(const ushort4*)h;
}

// Closed-form lane-parallel trace (R10, validated) + f16 octet-row gather.
__global__ __launch_bounds__(512)
void siddon_fused(const f16_t* __restrict__ v16, float* __restrict__ out)
{
    __shared__ int2 sEnt[TILE][NENT];  // .x = BYTE offset of f16 vol row, .y = weight bits
    __shared__ int  sCnt[TILE];        // valid count padded to multiple of 32

    const int tid  = threadIdx.x;
    const int wid  = tid >> 6;         // wave = ray-in-tile (all 8 waves trace)
    const int lane = tid & 63;
    const int tile = blockIdx.x;
    const int ray  = tile * TILE + wid;
    const int a    = ray / NU;
    const int u    = ray - a * NU;

    const float EPSf = 1e-12f;
    const float INFp = __builtin_inff();
    const float DIAG = 1.41421356237309514547f;

    // ---------------- per-ray setup (wave-uniform) ----------------
    const float ang = (float)a * (float)(3.14159265358979323846 / 90.0);
    const float dx = (float)cos((double)ang);
    const float dy = (float)sin((double)ang);
    const float uu = (float)u - 47.5f;
    const float x0 = __fmul_rn(-uu, dy);
    const float y0 = __fmul_rn( uu, dx);

    const float xmin = -47.5f, xmax = 47.5f;
    const float ymin = -47.5f, ymax = 47.5f;

    float tx0, tx1;
    {
        const bool par = fabsf(dx) < EPSf;
        const float safe = par ? 1.0f : dx;
        const float t0 = __fdiv_rn(xmin - x0, safe);
        const float t1 = __fdiv_rn(xmax - x0, safe);
        const float lo = fminf(t0, t1), hi = fmaxf(t0, t1);
        const bool inside = (x0 >= xmin) && (x0 <= xmax);
        tx0 = par ? (inside ? -INFp : INFp) : lo;
        tx1 = par ? (inside ?  INFp : -INFp) : hi;
    }
    float ty0, ty1;
    {
        const bool par = fabsf(dy) < EPSf;
        const float safe = par ? 1.0f : dy;
        const float t0 = __fdiv_rn(ymin - y0, safe);
        const float t1 = __fdiv_rn(ymax - y0, safe);
        const float lo = fminf(t0, t1), hi = fmaxf(t0, t1);
        const bool inside = (y0 >= ymin) && (y0 <= ymax);
        ty0 = par ? (inside ? -INFp : INFp) : lo;
        ty1 = par ? (inside ?  INFp : -INFp) : hi;
    }

    const float t_entry = fmaxf(tx0, ty0);
    const float t_exit  = fminf(tx1, ty1);
    const bool  alive0  = t_entry < t_exit;
    const float te  = alive0 ? t_entry : 0.0f;
    const float tex = alive0 ? t_exit  : 0.0f;

    const float xe = __fadd_rn(x0, __fmul_rn(te, dx));
    const float ye = __fadd_rn(y0, __fmul_rn(te, dy));
    const int i0 = (int)fminf(fmaxf(rintf(__fadd_rn(xe, 47.5f)), 0.0f), 95.0f);
    const int j0 = (int)fminf(fmaxf(rintf(__fadd_rn(ye, 47.5f)), 0.0f), 95.0f);

    const bool okx = fabsf(dx) > EPSf;
    const bool oky = fabsf(dy) > EPSf;
    const float inv_dx = okx ? __fdiv_rn(1.0f, dx) : 0.0f;
    const float inv_dy = oky ? __fdiv_rn(1.0f, dy) : 0.0f;
    const float wscale = __fdiv_rn(DIAG, fmaxf(fabsf(dx) + fabsf(dy), EPSf));
    const float tex_m_eps = __fadd_rn(tex, -EPSf);

    // APs of crossing times: Tx_k = Ax + k*px, Ty_m = Ay + m*py (absolute t).
    const float cx = (dx > 0.0f) ? -47.0f : -48.0f;
    const float cy = (dy > 0.0f) ? -47.0f : -48.0f;
    const float Ax = okx ? __fadd_rn(te, __fmul_rn(((float)i0 + cx) - xe, inv_dx)) : INFp;
    const float Ay = oky ? __fadd_rn(te, __fmul_rn(((float)j0 + cy) - ye, inv_dy)) : INFp;
    const float px = okx ? fabsf(inv_dx) : 0.0f;
    const float py = oky ? fabsf(inv_dy) : 0.0f;
    const int   si = (dx > 0.0f) ? 1 : -1;
    const int   sj = (dy > 0.0f) ? 1 : -1;

    const float inv_pq = __fdiv_rn(1.0f, px + py);
    const float Cc = Ay - Ax;

    // ---------------- lane-parallel trace: 4 rounds of 64 entries ----------------
    int2* __restrict__ myRow = &sEnt[wid][0];
    int cnt = 0;
    #pragma unroll
    for (int rnd = 0; rnd < 4; ++rnd) {
        const int n = (rnd << 6) + lane;
        const float nf = (float)n;

        float kf = __fmul_rn(__fmaf_rn(nf, py, Cc), inv_pq);
        kf = fminf(fmaxf(kf, 0.0f), nf);
        int k = (int)rintf(kf);

        #pragma unroll
        for (int it = 0; it < 4; ++it) {
            const int m = n - k;
            const float Txk   = __fmaf_rn((float)k, px, Ax);
            const float Txkm1 = (k > 0) ? __fmaf_rn((float)(k - 1), px, Ax) : -INFp;
            const float Tyl   = __fmaf_rn((float)m, py, Ay);
            const float Tylm1 = (m > 0) ? __fmaf_rn((float)(m - 1), py, Ay) : -INFp;
            const bool dec = (Txkm1 > Tyl);
            const bool inc = (!dec) && (Tylm1 > Txk);
            k += inc ? 1 : (dec ? -1 : 0);
        }

        const int m = n - k;
        const float Txk   = __fmaf_rn((float)k, px, Ax);
        const float Txkm1 = (k > 0) ? __fmaf_rn((float)(k - 1), px, Ax) : -INFp;
        const float Tyl   = __fmaf_rn((float)m, py, Ay);
        const float Tylm1 = (m > 0) ? __fmaf_rn((float)(m - 1), py, Ay) : -INFp;

        const float Tn   = fminf(Txk, Tyl);
        const float prev = fmaxf(te, fmaxf(Txkm1, Tylm1));
        const float dt   = __fadd_rn(fminf(Tn, tex), -fminf(prev, tex));
        const bool active = alive0 && (prev < tex_m_eps);
        float w = __fmul_rn(fmaxf(0.0f, dt), wscale);
        w = active ? w : 0.0f;

        const int ii = min(95, max(0, i0 + ((si > 0) ? k : -k)));
        const int jj = min(95, max(0, j0 + ((sj > 0) ? m : -m)));
        int2 e;
        e.x = (ii * NH + jj) << 7;             // BYTE offset into f16 vol (128B rows)
        e.y = __float_as_int(w);
        myRow[n] = e;

        cnt += (int)__popcll(__ballot(active));
    }
    if (lane == 0) sCnt[wid] = min((cnt + 31) & ~31, CNTMAX);
    __syncthreads();

    // ---------------- gather: octet-row f16 ----------------
    // Lane L: row-in-octet r=L>>3, 16B chunk sub=L&7 (8 f16 = v in [sub*8, sub*8+8)).
    // One dwordx4 per lane per entry-octet => 8 vol rows per wave-instruction.
    const int r   = lane >> 3;
    const int sub = lane & 7;
    const int subOff = sub << 4;

    const int cap = sCnt[wid];
    const int2* __restrict__ eRow = &sEnt[wid][r];   // entry n+r at [n]
    const char* __restrict__ vb   = (const char*)v16;

    float acc[8] = {0, 0, 0, 0, 0, 0, 0, 0};
    for (int n = 0; n < cap; n += 32) {
        #pragma unroll
        for (int b = 0; b < 4; ++b) {            // 4 loads in flight per wave
            const int2 e = eRow[n + b * 8];      // 16-bank LDS broadcast
            const float w = __int_as_float(e.y);
            const uint4 q = *(const uint4*)(vb + (e.x + subOff));
            const f16_t* h = (const f16_t*)&q;   // 8 f16 v-values
            #pragma unroll
            for (int k = 0; k < 8; ++k)
                acc[k] = fmaf(w, (float)h[k], acc[k]);   // v_fma_mix / cvt+fma
        }
    }

    // reduce across the 8 row groups (lanes differing in bits 3..5)
    #pragma unroll
    for (int k = 0; k < 8; ++k) {
        acc[k] += __shfl_xor(acc[k], 8, 64);
        acc[k] += __shfl_xor(acc[k], 16, 64);
        acc[k] += __shfl_xor(acc[k], 32, 64);
    }

    if (lane < 8) {                               // lane == sub, v = sub*8..sub*8+7
        float* dst = out + (u * NA + a) * NV + (sub << 3);
        float4 lo; lo.x = acc[0]; lo.y = acc[1]; lo.z = acc[2]; lo.w = acc[3];
        float4 hi; hi.x = acc[4]; hi.y = acc[5]; hi.z = acc[6]; hi.w = acc[7];
        *(float4*)dst = lo;                       // 8 lanes x 32B = 256B coalesced
        *(float4*)(dst + 4) = hi;
    }
}

extern "C" void kernel_launch(void* const* d_in, const int* in_sizes, int n_in,
                              void* d_out, int out_size, void* d_ws, size_t ws_size,
                              hipStream_t stream) {
    const float* vol = (const float*)d_in[0];
    float* out = (float*)d_out;
    f16_t* v16 = (f16_t*)d_ws;                    // 1.18 MB (ws is ~268 MB, proven R2/R3/R6)
    hipLaunchKernelGGL(vol_to_f16, dim3(NVOX / 4 / 256), dim3(256), 0, stream, vol, v16);
    hipLaunchKernelGGL(siddon_fused, dim3(NBLK), dim3(512), 0, stream, v16, out);
}

// Round 12
// 70.216 us; speedup vs baseline: 1.0505x; 1.0505x over previous
//
#include <hip/hip_runtime.h>
#include <math.h>

// Problem constants (from reference):
//   vol: (B=1, C=1, W=96, H=96, D=64) float32, row-major -> vol[(x*96+y)*64+z]
//   out: (B,C,U=96,A=90,V=64) float32 -> out[(u*90+a)*64+v]
namespace {
constexpr int NA = 90, NU = 96, NV = 64, NW = 96, NH = 96, ND = 64;
constexpr int NRAY   = NA * NU;      // 8640
constexpr int NENT   = 256;          // entries per ray (4 rounds x 64 lanes)
constexpr int CNTMAX = 208;          // gather cap (valid count <= ~196 structurally)
constexpr int TILE   = 8;            // rays per block = waves per block
constexpr int NBLK   = NRAY / TILE;  // 1080 blocks (~4.2/CU)
}

// R12: explicit register software pipeline in the gather.
// Evidence chain: R8 warm re-gather = 3.7us marginal; R7 (4x fewer VMEM) and
// R11 (2x fewer bytes, f16) both NEUTRAL -> the ~15us excess is cold-cache
// LATENCY exposure (the harness's 268MB ws-poison sweeps L2/L3 every iter),
// serialized by the per-iteration ds_read(entry) -> addr -> global_load -> fma
// chain that the compiler does not pipeline across the backedge.
// Fix: entries prefetched TWO batches ahead (LDS), vol rows ONE batch ahead
// (4 dwordx4 perpetually in flight, issued a full iteration before use).
// Trace: R10's closed-form lane-parallel merge-of-APs (validated, absmax 0.25).
__global__ __launch_bounds__(512)
void siddon_fused(const float* __restrict__ vol, float* __restrict__ out)
{
    __shared__ int2 sEnt[TILE][NENT];  // .x = BYTE offset of vol row, .y = weight bits
    __shared__ int  sCnt[TILE];        // valid count, padded to x16, >=16

    const int tid  = threadIdx.x;
    const int wid  = tid >> 6;         // wave = ray-in-tile (all 8 waves trace)
    const int lane = tid & 63;
    const int tile = blockIdx.x;
    const int ray  = tile * TILE + wid;
    const int a    = ray / NU;
    const int u    = ray - a * NU;

    const float EPSf = 1e-12f;
    const float INFp = __builtin_inff();
    const float DIAG = 1.41421356237309514547f;

    // ---------------- per-ray setup (wave-uniform) ----------------
    const float ang = (float)a * (float)(3.14159265358979323846 / 90.0);
    const float dx = (float)cos((double)ang);
    const float dy = (float)sin((double)ang);
    const float uu = (float)u - 47.5f;
    const float x0 = __fmul_rn(-uu, dy);
    const float y0 = __fmul_rn( uu, dx);

    const float xmin = -47.5f, xmax = 47.5f;
    const float ymin = -47.5f, ymax = 47.5f;

    float tx0, tx1;
    {
        const bool par = fabsf(dx) < EPSf;
        const float safe = par ? 1.0f : dx;
        const float t0 = __fdiv_rn(xmin - x0, safe);
        const float t1 = __fdiv_rn(xmax - x0, safe);
        const float lo = fminf(t0, t1), hi = fmaxf(t0, t1);
        const bool inside = (x0 >= xmin) && (x0 <= xmax);
        tx0 = par ? (inside ? -INFp : INFp) : lo;
        tx1 = par ? (inside ?  INFp : -INFp) : hi;
    }
    float ty0, ty1;
    {
        const bool par = fabsf(dy) < EPSf;
        const float safe = par ? 1.0f : dy;
        const float t0 = __fdiv_rn(ymin - y0, safe);
        const float t1 = __fdiv_rn(ymax - y0, safe);
        const float lo = fminf(t0, t1), hi = fmaxf(t0, t1);
        const bool inside = (y0 >= ymin) && (y0 <= ymax);
        ty0 = par ? (inside ? -INFp : INFp) : lo;
        ty1 = par ? (inside ?  INFp : -INFp) : hi;
    }

    const float t_entry = fmaxf(tx0, ty0);
    const float t_exit  = fminf(tx1, ty1);
    const bool  alive0  = t_entry < t_exit;
    const float te  = alive0 ? t_entry : 0.0f;
    const float tex = alive0 ? t_exit  : 0.0f;

    const float xe = __fadd_rn(x0, __fmul_rn(te, dx));
    const float ye = __fadd_rn(y0, __fmul_rn(te, dy));
    const int i0 = (int)fminf(fmaxf(rintf(__fadd_rn(xe, 47.5f)), 0.0f), 95.0f);
    const int j0 = (int)fminf(fmaxf(rintf(__fadd_rn(ye, 47.5f)), 0.0f), 95.0f);

    const bool okx = fabsf(dx) > EPSf;
    const bool oky = fabsf(dy) > EPSf;
    const float inv_dx = okx ? __fdiv_rn(1.0f, dx) : 0.0f;
    const float inv_dy = oky ? __fdiv_rn(1.0f, dy) : 0.0f;
    const float wscale = __fdiv_rn(DIAG, fmaxf(fabsf(dx) + fabsf(dy), EPSf));
    const float tex_m_eps = __fadd_rn(tex, -EPSf);

    // APs of crossing times: Tx_k = Ax + k*px, Ty_m = Ay + m*py (absolute t).
    const float cx = (dx > 0.0f) ? -47.0f : -48.0f;
    const float cy = (dy > 0.0f) ? -47.0f : -48.0f;
    const float Ax = okx ? __fadd_rn(te, __fmul_rn(((float)i0 + cx) - xe, inv_dx)) : INFp;
    const float Ay = oky ? __fadd_rn(te, __fmul_rn(((float)j0 + cy) - ye, inv_dy)) : INFp;
    const float px = okx ? fabsf(inv_dx) : 0.0f;
    const float py = oky ? fabsf(inv_dy) : 0.0f;
    const int   si = (dx > 0.0f) ? 1 : -1;
    const int   sj = (dy > 0.0f) ? 1 : -1;

    const float inv_pq = __fdiv_rn(1.0f, px + py);
    const float Cc = Ay - Ax;

    // ---------------- lane-parallel trace: 4 rounds of 64 entries ----------------
    int2* __restrict__ myRow = &sEnt[wid][0];
    int cnt = 0;
    #pragma unroll
    for (int rnd = 0; rnd < 4; ++rnd) {
        const int n = (rnd << 6) + lane;
        const float nf = (float)n;

        float kf = __fmul_rn(__fmaf_rn(nf, py, Cc), inv_pq);
        kf = fminf(fmaxf(kf, 0.0f), nf);       // also collapses +-INF safely
        int k = (int)rintf(kf);

        // partition fixup: valid iff Tx_{k-1} <= Ty_{n-k} and Ty_{n-k-1} <= Tx_k.
        #pragma unroll
        for (int it = 0; it < 4; ++it) {
            const int m = n - k;
            const float Txk   = __fmaf_rn((float)k, px, Ax);
            const float Txkm1 = (k > 0) ? __fmaf_rn((float)(k - 1), px, Ax) : -INFp;
            const float Tyl   = __fmaf_rn((float)m, py, Ay);
            const float Tylm1 = (m > 0) ? __fmaf_rn((float)(m - 1), py, Ay) : -INFp;
            const bool dec = (Txkm1 > Tyl);
            const bool inc = (!dec) && (Tylm1 > Txk);
            k += inc ? 1 : (dec ? -1 : 0);
        }

        const int m = n - k;
        const float Txk   = __fmaf_rn((float)k, px, Ax);
        const float Txkm1 = (k > 0) ? __fmaf_rn((float)(k - 1), px, Ax) : -INFp;
        const float Tyl   = __fmaf_rn((float)m, py, Ay);
        const float Tylm1 = (m > 0) ? __fmaf_rn((float)(m - 1), py, Ay) : -INFp;

        const float Tn   = fminf(Txk, Tyl);                 // event ending segment n
        const float prev = fmaxf(te, fmaxf(Txkm1, Tylm1));  // event starting it
        const float dt   = __fadd_rn(fminf(Tn, tex), -fminf(prev, tex));
        const bool active = alive0 && (prev < tex_m_eps);
        float w = __fmul_rn(fmaxf(0.0f, dt), wscale);
        w = active ? w : 0.0f;

        const int ii = min(95, max(0, i0 + ((si > 0) ? k : -k)));
        const int jj = min(95, max(0, j0 + ((sj > 0) ? m : -m)));
        int2 e;
        e.x = (ii * NH + jj) << 8;             // BYTE offset into vol (256B rows)
        e.y = __float_as_int(w);
        myRow[n] = e;

        cnt += (int)__popcll(__ballot(active));
    }
    if (lane == 0) {
        const int c = (cnt + 15) & ~15;
        sCnt[wid] = min(max(c, 16), CNTMAX);   // >=16 so pipeline indices stay valid
    }
    __syncthreads();

    // ---------------- gather: quad-row, register-software-pipelined ----------
    // Lane L: row-in-quad r=L>>4, 16B chunk sub=L&15. One dwordx4 per 4 entries
    // fetches four 256B vol rows. Entries prefetched 2 batches ahead (LDS),
    // vol rows 1 batch ahead (VMEM stays 4-deep in flight continuously).
    const int r   = lane >> 4;
    const int sub = lane & 15;
    const int subOff = sub << 4;

    const int cap = sCnt[wid];                       // multiple of 16, in [16,208]
    const int2* __restrict__ eRow = &sEnt[wid][r];   // entry n+r at [n]
    const char* __restrict__ vb   = (const char*)vol;

    int2   E0[4], E1[4];
    float4 V0[4];
    #pragma unroll
    for (int b = 0; b < 4; ++b) E0[b] = eRow[b * 4];
    #pragma unroll
    for (int b = 0; b < 4; ++b) V0[b] = *(const float4*)(vb + (E0[b].x + subOff));
    const int nb1 = (cap > 16) ? 16 : 0;
    #pragma unroll
    for (int b = 0; b < 4; ++b) E1[b] = eRow[nb1 + b * 4];

    float4 acc[4] = {{0,0,0,0}, {0,0,0,0}, {0,0,0,0}, {0,0,0,0}};
    for (int n = 0; n < cap; n += 16) {
        // issue next batch's vol loads (addresses already in regs -> no LDS wait)
        float4 V1[4];
        #pragma unroll
        for (int b = 0; b < 4; ++b) V1[b] = *(const float4*)(vb + (E1[b].x + subOff));
        // prefetch entries two batches ahead (clamped; harmless re-read at tail)
        const int n2 = min(n + 32, cap - 16);
        int2 E2[4];
        #pragma unroll
        for (int b = 0; b < 4; ++b) E2[b] = eRow[n2 + b * 4];
        // consume current batch (loads issued a full iteration ago)
        #pragma unroll
        for (int b = 0; b < 4; ++b) {
            const float w = __int_as_float(E0[b].y);
            acc[b].x = fmaf(w, V0[b].x, acc[b].x);
            acc[b].y = fmaf(w, V0[b].y, acc[b].y);
            acc[b].z = fmaf(w, V0[b].z, acc[b].z);
            acc[b].w = fmaf(w, V0[b].w, acc[b].w);
        }
        // shift pipeline
        #pragma unroll
        for (int b = 0; b < 4; ++b) { E0[b] = E1[b]; V0[b] = V1[b]; E1[b] = E2[b]; }
    }

    float sx = (acc[0].x + acc[1].x) + (acc[2].x + acc[3].x);
    float sy = (acc[0].y + acc[1].y) + (acc[2].y + acc[3].y);
    float sz = (acc[0].z + acc[1].z) + (acc[2].z + acc[3].z);
    float sw = (acc[0].w + acc[1].w) + (acc[2].w + acc[3].w);

    // reduce across the 4 row groups: lanes {sub, 16+sub, 32+sub, 48+sub}
    sx += __shfl_xor(sx, 16, 64);  sy += __shfl_xor(sy, 16, 64);
    sz += __shfl_xor(sz, 16, 64);  sw += __shfl_xor(sw, 16, 64);
    sx += __shfl_xor(sx, 32, 64);  sy += __shfl_xor(sy, 32, 64);
    sz += __shfl_xor(sz, 32, 64);  sw += __shfl_xor(sw, 32, 64);

    if (lane < 16) {
        float4 res; res.x = sx; res.y = sy; res.z = sz; res.w = sw;
        *(float4*)(out + (u * NA + a) * NV + (sub << 2)) = res;  // 256B coalesced
    }
}

extern "C" void kernel_launch(void* const* d_in, const int* in_sizes, int n_in,
                              void* d_out, int out_size, void* d_ws, size_t ws_size,
                              hipStream_t stream) {
    const float* vol = (const float*)d_in[0];
    float* out = (float*)d_out;
    hipLaunchKernelGGL(siddon_fused, dim3(NBLK), dim3(512), 0, stream, vol, out);
}

// Round 13
// 69.817 us; speedup vs baseline: 1.0565x; 1.0057x over previous
//
#include <hip/hip_runtime.h>
#include <math.h>

// Problem constants (from reference):
//   vol: (B=1, C=1, W=96, H=96, D=64) float32, row-major -> vol[(x*96+y)*64+z]
//   out: (B,C,U=96,A=90,V=64) float32 -> out[(u*90+a)*64+v]
namespace {
constexpr int NA = 90, NU = 96, NV = 64, NW = 96, NH = 96, ND = 64;
constexpr int NRAY   = NA * NU;      // 8640
constexpr int NENT   = 256;          // entries per ray (4 rounds x 64 lanes)
constexpr int CNTMAX = 208;          // gather cap (valid count <= ~196 structurally)
constexpr int TILE   = 8;            // rays per block = waves per block
constexpr int NBLK   = NRAY / TILE;  // 1080 blocks (~4.2/CU)
}

// R13: barrier-free trace->gather. Since R10 each wave writes AND reads only
// its own LDS row (sEnt[wid]) -> the inter-phase __syncthreads is unnecessary
// (intra-wave LDS ordering via lgkmcnt). Removing it (a) de-synchronizes the
// 8 waves' cold-load bursts, (b) removes the scheduling wall so the compiler
// can hoist early gather batches' LDS reads + vol loads above trace rounds
// 1-3 (disjoint LDS offsets), overlapping trace VALU with vol-load latency.
// sCnt LDS round-trip dropped: the count is already wave-uniform (popc of
// ballot). Trace = R10 closed-form merge-of-APs (validated, absmax 0.25);
// gather = R12 quad-row 1-deep pipeline (validated equal-best).
__global__ __launch_bounds__(512)
void siddon_fused(const float* __restrict__ vol, float* __restrict__ out)
{
    __shared__ int2 sEnt[TILE][NENT];  // .x = BYTE offset of vol row, .y = weight bits

    const int tid  = threadIdx.x;
    const int wid  = tid >> 6;         // wave = ray-in-tile (all 8 waves trace)
    const int lane = tid & 63;
    const int tile = blockIdx.x;
    const int ray  = tile * TILE + wid;
    const int a    = ray / NU;
    const int u    = ray - a * NU;

    const float EPSf = 1e-12f;
    const float INFp = __builtin_inff();
    const float DIAG = 1.41421356237309514547f;

    // ---------------- per-ray setup (wave-uniform) ----------------
    const float ang = (float)a * (float)(3.14159265358979323846 / 90.0);
    const float dx = (float)cos((double)ang);   // f64 then round: matches numpy
    const float dy = (float)sin((double)ang);   // bit-exactly (keeps i0/j0 knife-
    const float uu = (float)u - 47.5f;          // edges on the reference's side)
    const float x0 = __fmul_rn(-uu, dy);
    const float y0 = __fmul_rn( uu, dx);

    const float xmin = -47.5f, xmax = 47.5f;
    const float ymin = -47.5f, ymax = 47.5f;

    float tx0, tx1;
    {
        const bool par = fabsf(dx) < EPSf;
        const float safe = par ? 1.0f : dx;
        const float t0 = __fdiv_rn(xmin - x0, safe);
        const float t1 = __fdiv_rn(xmax - x0, safe);
        const float lo = fminf(t0, t1), hi = fmaxf(t0, t1);
        const bool inside = (x0 >= xmin) && (x0 <= xmax);
        tx0 = par ? (inside ? -INFp : INFp) : lo;
        tx1 = par ? (inside ?  INFp : -INFp) : hi;
    }
    float ty0, ty1;
    {
        const bool par = fabsf(dy) < EPSf;
        const float safe = par ? 1.0f : dy;
        const float t0 = __fdiv_rn(ymin - y0, safe);
        const float t1 = __fdiv_rn(ymax - y0, safe);
        const float lo = fminf(t0, t1), hi = fmaxf(t0, t1);
        const bool inside = (y0 >= ymin) && (y0 <= ymax);
        ty0 = par ? (inside ? -INFp : INFp) : lo;
        ty1 = par ? (inside ?  INFp : -INFp) : hi;
    }

    const float t_entry = fmaxf(tx0, ty0);
    const float t_exit  = fminf(tx1, ty1);
    const bool  alive0  = t_entry < t_exit;
    const float te  = alive0 ? t_entry : 0.0f;
    const float tex = alive0 ? t_exit  : 0.0f;

    const float xe = __fadd_rn(x0, __fmul_rn(te, dx));
    const float ye = __fadd_rn(y0, __fmul_rn(te, dy));
    const int i0 = (int)fminf(fmaxf(rintf(__fadd_rn(xe, 47.5f)), 0.0f), 95.0f);
    const int j0 = (int)fminf(fmaxf(rintf(__fadd_rn(ye, 47.5f)), 0.0f), 95.0f);

    const bool okx = fabsf(dx) > EPSf;
    const bool oky = fabsf(dy) > EPSf;
    const float inv_dx = okx ? __fdiv_rn(1.0f, dx) : 0.0f;
    const float inv_dy = oky ? __fdiv_rn(1.0f, dy) : 0.0f;
    const float wscale = __fdiv_rn(DIAG, fmaxf(fabsf(dx) + fabsf(dy), EPSf));
    const float tex_m_eps = __fadd_rn(tex, -EPSf);

    // APs of crossing times: Tx_k = Ax + k*px, Ty_m = Ay + m*py (absolute t).
    const float cx = (dx > 0.0f) ? -47.0f : -48.0f;
    const float cy = (dy > 0.0f) ? -47.0f : -48.0f;
    const float Ax = okx ? __fadd_rn(te, __fmul_rn(((float)i0 + cx) - xe, inv_dx)) : INFp;
    const float Ay = oky ? __fadd_rn(te, __fmul_rn(((float)j0 + cy) - ye, inv_dy)) : INFp;
    const float px = okx ? fabsf(inv_dx) : 0.0f;
    const float py = oky ? fabsf(inv_dy) : 0.0f;
    const int   si = (dx > 0.0f) ? 1 : -1;
    const int   sj = (dy > 0.0f) ? 1 : -1;

    const float inv_pq = __fdiv_rn(1.0f, px + py);
    const float Cc = Ay - Ax;

    // ---------------- lane-parallel trace: 4 rounds of 64 entries ----------------
    int2* __restrict__ myRow = &sEnt[wid][0];
    int cnt = 0;
    #pragma unroll
    for (int rnd = 0; rnd < 4; ++rnd) {
        const int n = (rnd << 6) + lane;
        const float nf = (float)n;

        float kf = __fmul_rn(__fmaf_rn(nf, py, Cc), inv_pq);
        kf = fminf(fmaxf(kf, 0.0f), nf);       // also collapses +-INF safely
        int k = (int)rintf(kf);

        // partition fixup: valid iff Tx_{k-1} <= Ty_{n-k} and Ty_{n-k-1} <= Tx_k.
        #pragma unroll
        for (int it = 0; it < 4; ++it) {
            const int m = n - k;
            const float Txk   = __fmaf_rn((float)k, px, Ax);
            const float Txkm1 = (k > 0) ? __fmaf_rn((float)(k - 1), px, Ax) : -INFp;
            const float Tyl   = __fmaf_rn((float)m, py, Ay);
            const float Tylm1 = (m > 0) ? __fmaf_rn((float)(m - 1), py, Ay) : -INFp;
            const bool dec = (Txkm1 > Tyl);
            const bool inc = (!dec) && (Tylm1 > Txk);
            k += inc ? 1 : (dec ? -1 : 0);
        }

        const int m = n - k;
        const float Txk   = __fmaf_rn((float)k, px, Ax);
        const float Txkm1 = (k > 0) ? __fmaf_rn((float)(k - 1), px, Ax) : -INFp;
        const float Tyl   = __fmaf_rn((float)m, py, Ay);
        const float Tylm1 = (m > 0) ? __fmaf_rn((float)(m - 1), py, Ay) : -INFp;

        const float Tn   = fminf(Txk, Tyl);                 // event ending segment n
        const float prev = fmaxf(te, fmaxf(Txkm1, Tylm1));  // event starting it
        const float dt   = __fadd_rn(fminf(Tn, tex), -fminf(prev, tex));
        const bool active = alive0 && (prev < tex_m_eps);
        float w = __fmul_rn(fmaxf(0.0f, dt), wscale);
        w = active ? w : 0.0f;

        const int ii = min(95, max(0, i0 + ((si > 0) ? k : -k)));
        const int jj = min(95, max(0, j0 + ((sj > 0) ? m : -m)));
        int2 e;
        e.x = (ii * NH + jj) << 8;             // BYTE offset into vol (256B rows)
        e.y = __float_as_int(w);
        myRow[n] = e;

        cnt += (int)__popcll(__ballot(active));
    }
    // cap is WAVE-UNIFORM (popc of ballots) -> stays in SGPRs, no LDS, no barrier.
    const int cap = min(max((cnt + 15) & ~15, 16), CNTMAX);

    // NO __syncthreads(): sEnt[wid] is wave-private (written and read by wave
    // wid only); intra-wave LDS ordering is guaranteed by lgkmcnt. This also
    // lets the scheduler hoist early gather loads above later trace rounds.

    // ---------------- gather: quad-row, 1-deep register pipeline ----------
    // Lane L: row-in-quad r=L>>4, 16B chunk sub=L&15. One dwordx4 per 4 entries
    // fetches four 256B vol rows.
    const int r   = lane >> 4;
    const int sub = lane & 15;
    const int subOff = sub << 4;

    const int2* __restrict__ eRow = &sEnt[wid][r];   // entry n+r at [n]
    const char* __restrict__ vb   = (const char*)vol;

    int2   E0[4], E1[4];
    float4 V0[4];
    #pragma unroll
    for (int b = 0; b < 4; ++b) E0[b] = eRow[b * 4];
    #pragma unroll
    for (int b = 0; b < 4; ++b) V0[b] = *(const float4*)(vb + (E0[b].x + subOff));
    const int nb1 = (cap > 16) ? 16 : 0;
    #pragma unroll
    for (int b = 0; b < 4; ++b) E1[b] = eRow[nb1 + b * 4];

    float4 acc[4] = {{0,0,0,0}, {0,0,0,0}, {0,0,0,0}, {0,0,0,0}};
    for (int n = 0; n < cap; n += 16) {
        // issue next batch's vol loads (addresses already in regs)
        float4 V1[4];
        #pragma unroll
        for (int b = 0; b < 4; ++b) V1[b] = *(const float4*)(vb + (E1[b].x + subOff));
        // prefetch entries two batches ahead (clamped; harmless re-read at tail)
        const int n2 = min(n + 32, cap - 16);
        int2 E2[4];
        #pragma unroll
        for (int b = 0; b < 4; ++b) E2[b] = eRow[n2 + b * 4];
        // consume current batch (loads issued a full iteration ago)
        #pragma unroll
        for (int b = 0; b < 4; ++b) {
            const float w = __int_as_float(E0[b].y);
            acc[b].x = fmaf(w, V0[b].x, acc[b].x);
            acc[b].y = fmaf(w, V0[b].y, acc[b].y);
            acc[b].z = fmaf(w, V0[b].z, acc[b].z);
            acc[b].w = fmaf(w, V0[b].w, acc[b].w);
        }
        // shift pipeline
        #pragma unroll
        for (int b = 0; b < 4; ++b) { E0[b] = E1[b]; V0[b] = V1[b]; E1[b] = E2[b]; }
    }

    float sx = (acc[0].x + acc[1].x) + (acc[2].x + acc[3].x);
    float sy = (acc[0].y + acc[1].y) + (acc[2].y + acc[3].y);
    float sz = (acc[0].z + acc[1].z) + (acc[2].z + acc[3].z);
    float sw = (acc[0].w + acc[1].w) + (acc[2].w + acc[3].w);

    // reduce across the 4 row groups: lanes {sub, 16+sub, 32+sub, 48+sub}
    sx += __shfl_xor(sx, 16, 64);  sy += __shfl_xor(sy, 16, 64);
    sz += __shfl_xor(sz, 16, 64);  sw += __shfl_xor(sw, 16, 64);
    sx += __shfl_xor(sx, 32, 64);  sy += __shfl_xor(sy, 32, 64);
    sz += __shfl_xor(sz, 32, 64);  sw += __shfl_xor(sw, 32, 64);

    if (lane < 16) {
        float4 res; res.x = sx; res.y = sy; res.z = sz; res.w = sw;
        *(float4*)(out + (u * NA + a) * NV + (sub << 2)) = res;  // 256B coalesced
    }
}

extern "C" void kernel_launch(void* const* d_in, const int* in_sizes, int n_in,
                              void* d_out, int out_size, void* d_ws, size_t ws_size,
                              hipStream_t stream) {
    const float* vol = (const float*)d_in[0];
    float* out = (float*)d_out;
    hipLaunchKernelGGL(siddon_fused, dim3(NBLK), dim3(512), 0, stream, vol, out);
}

// Round 14
// 67.918 us; speedup vs baseline: 1.0860x; 1.0280x over previous
//
#include <hip/hip_runtime.h>
#include <math.h>

// Problem constants (from reference):
//   vol: (B=1, C=1, W=96, H=96, D=64) float32, row-major -> vol[(x*96+y)*64+z]
//   out: (B,C,U=96,A=90,V=64) float32 -> out[(u*90+a)*64+v]
namespace {
constexpr int NA = 90, NU = 96, NV = 64, NW = 96, NH = 96, ND = 64;
constexpr int NRAY   = NA * NU;      // 8640
constexpr int NVOX   = NW * NH * ND; // 589824
constexpr int NENT   = 256;          // entries per ray (4 rounds x 64 lanes)
constexpr int CNTMAX = 208;          // gather cap (valid count <= ~196 structurally)
constexpr int TILE   = 8;            // rays per block = waves per block
constexpr int NBLK   = NRAY / TILE;  // 1080 blocks (~4.2/CU)
}

// Compact branch-free f64 sincos (fdlibm kernel polys, |err| ~3e-16).
// Replaces __ocml sin/cos calls: f32-rounds identically to numpy's
// (double->float) values except within ~1e-16 of a rounding boundary.
__device__ inline void sincos_poly(double xd, float* s, float* c)
{
    const double INV_PIO2 = 0.63661977236758134308;
    const double PIO2_HI  = 1.57079632679489655800e+00;
    const double PIO2_LO  = 6.12323399573676603587e-17;
    const double qd = rint(xd * INV_PIO2);            // 0,1,2 for xd in [0, 3.11)
    const double r  = (xd - qd * PIO2_HI) - qd * PIO2_LO;
    const double z  = r * r;
    const double sp = r + (r * z) * (-1.66666666666666324348e-01 + z *
                     ( 8.33333333332248946124e-03 + z *
                     (-1.98412698298579493134e-04 + z *
                     ( 2.75573137070700676789e-06 + z *
                     (-2.50507602534068634195e-08 + z *
                       1.58969099521155010221e-10)))));
    const double cp = 1.0 + z * (-0.5 + z *
                     ( 4.16666666666666019037e-02 + z *
                     (-1.38888888888741095749e-03 + z *
                     ( 2.48015872894767294178e-05 + z *
                     (-2.75573143513906633035e-07 + z *
                     ( 2.08757232129817482790e-09 + z *
                      -1.13596475577881948265e-11))))));
    const int q = (int)qd;
    const double sv = (q == 0) ? sp : ((q == 1) ? cp : -sp);
    const double cv = (q == 0) ? cp : ((q == 1) ? -sp : -cp);
    *s = (float)sv;
    *c = (float)cv;
}

// R14: warm the memory hierarchy during the trace. R7/R11/R12/R13 falsified
// VMEM-count, byte-count, SWP-depth and barrier levers (all ~70us). Residual
// theory: the harness's 268MB ws-poison sweeps L2+L3 every iter, so gather's
// first touch of every vol line is a ~900cyc HBM miss, burst-serialized when
// all waves enter the gather together. Fix: 2 dwordx4 prefetch loads/thread
// at kernel top (block-group tile>>3 covers vol per-XCD; at worst warms L3
// for everyone), consumed by an empty asm AFTER the trace -> latency hidden
// behind trace VALU. Trace = R10 closed-form merge-of-APs (validated);
// gather = R10 simple quad-row (equal to R12's pipeline, fewer VGPRs).
__global__ __launch_bounds__(512)
void siddon_fused(const float* __restrict__ vol, float* __restrict__ out)
{
    __shared__ int2 sEnt[TILE][NENT];  // .x = BYTE offset of vol row, .y = weight bits

    const int tid  = threadIdx.x;
    const int wid  = tid >> 6;         // wave = ray-in-tile (all 8 waves trace)
    const int lane = tid & 63;
    const int tile = blockIdx.x;
    const int ray  = tile * TILE + wid;
    const int a    = ray / NU;
    const int u    = ray - a * NU;

    // ---- early vol prefetch (issued before setup; consumed after trace) ----
    float4 wA = {0, 0, 0, 0}, wB = {0, 0, 0, 0};
    {
        const int nchunks = NVOX / 4;          // 147456 float4 lines of vol
        const int base = (tile >> 3) * 1093;   // 135 groups x 1093 chunks ~ full vol
        const int iA = base + tid;
        const int iB = base + 512 + tid;
        const int hi = min(base + 1093, nchunks);
        if (iA < hi) wA = *(const float4*)(vol + (size_t)iA * 4);
        if (iB < hi) wB = *(const float4*)(vol + (size_t)iB * 4);
    }

    const float EPSf = 1e-12f;
    const float INFp = __builtin_inff();
    const float DIAG = 1.41421356237309514547f;

    // ---------------- per-ray setup (wave-uniform) ----------------
    const float ang = (float)a * (float)(3.14159265358979323846 / 90.0);
    float dy, dx;
    sincos_poly((double)ang, &dy, &dx);        // dx = cos, dy = sin (f32-exact)
    const float uu = (float)u - 47.5f;
    const float x0 = __fmul_rn(-uu, dy);
    const float y0 = __fmul_rn( uu, dx);

    const float xmin = -47.5f, xmax = 47.5f;
    const float ymin = -47.5f, ymax = 47.5f;

    float tx0, tx1;
    {
        const bool par = fabsf(dx) < EPSf;
        const float safe = par ? 1.0f : dx;
        const float t0 = __fdiv_rn(xmin - x0, safe);
        const float t1 = __fdiv_rn(xmax - x0, safe);
        const float lo = fminf(t0, t1), hi = fmaxf(t0, t1);
        const bool inside = (x0 >= xmin) && (x0 <= xmax);
        tx0 = par ? (inside ? -INFp : INFp) : lo;
        tx1 = par ? (inside ?  INFp : -INFp) : hi;
    }
    float ty0, ty1;
    {
        const bool par = fabsf(dy) < EPSf;
        const float safe = par ? 1.0f : dy;
        const float t0 = __fdiv_rn(ymin - y0, safe);
        const float t1 = __fdiv_rn(ymax - y0, safe);
        const float lo = fminf(t0, t1), hi = fmaxf(t0, t1);
        const bool inside = (y0 >= ymin) && (y0 <= ymax);
        ty0 = par ? (inside ? -INFp : INFp) : lo;
        ty1 = par ? (inside ?  INFp : -INFp) : hi;
    }

    const float t_entry = fmaxf(tx0, ty0);
    const float t_exit  = fminf(tx1, ty1);
    const bool  alive0  = t_entry < t_exit;
    const float te  = alive0 ? t_entry : 0.0f;
    const float tex = alive0 ? t_exit  : 0.0f;

    const float xe = __fadd_rn(x0, __fmul_rn(te, dx));
    const float ye = __fadd_rn(y0, __fmul_rn(te, dy));
    const int i0 = (int)fminf(fmaxf(rintf(__fadd_rn(xe, 47.5f)), 0.0f), 95.0f);
    const int j0 = (int)fminf(fmaxf(rintf(__fadd_rn(ye, 47.5f)), 0.0f), 95.0f);

    const bool okx = fabsf(dx) > EPSf;
    const bool oky = fabsf(dy) > EPSf;
    const float inv_dx = okx ? __fdiv_rn(1.0f, dx) : 0.0f;
    const float inv_dy = oky ? __fdiv_rn(1.0f, dy) : 0.0f;
    const float wscale = __fdiv_rn(DIAG, fmaxf(fabsf(dx) + fabsf(dy), EPSf));
    const float tex_m_eps = __fadd_rn(tex, -EPSf);

    // APs of crossing times: Tx_k = Ax + k*px, Ty_m = Ay + m*py (absolute t).
    const float cx = (dx > 0.0f) ? -47.0f : -48.0f;
    const float cy = (dy > 0.0f) ? -47.0f : -48.0f;
    const float Ax = okx ? __fadd_rn(te, __fmul_rn(((float)i0 + cx) - xe, inv_dx)) : INFp;
    const float Ay = oky ? __fadd_rn(te, __fmul_rn(((float)j0 + cy) - ye, inv_dy)) : INFp;
    const float px = okx ? fabsf(inv_dx) : 0.0f;
    const float py = oky ? fabsf(inv_dy) : 0.0f;
    const int   si = (dx > 0.0f) ? 1 : -1;
    const int   sj = (dy > 0.0f) ? 1 : -1;

    const float inv_pq = __fdiv_rn(1.0f, px + py);
    const float Cc = Ay - Ax;

    // ---------------- lane-parallel trace: 4 rounds of 64 entries ----------------
    int2* __restrict__ myRow = &sEnt[wid][0];
    int cnt = 0;
    #pragma unroll
    for (int rnd = 0; rnd < 4; ++rnd) {
        const int n = (rnd << 6) + lane;
        const float nf = (float)n;

        float kf = __fmul_rn(__fmaf_rn(nf, py, Cc), inv_pq);
        kf = fminf(fmaxf(kf, 0.0f), nf);       // also collapses +-INF safely
        int k = (int)rintf(kf);

        // partition fixup: valid iff Tx_{k-1} <= Ty_{n-k} and Ty_{n-k-1} <= Tx_k.
        #pragma unroll
        for (int it = 0; it < 4; ++it) {
            const int m = n - k;
            const float Txk   = __fmaf_rn((float)k, px, Ax);
            const float Txkm1 = (k > 0) ? __fmaf_rn((float)(k - 1), px, Ax) : -INFp;
            const float Tyl   = __fmaf_rn((float)m, py, Ay);
            const float Tylm1 = (m > 0) ? __fmaf_rn((float)(m - 1), py, Ay) : -INFp;
            const bool dec = (Txkm1 > Tyl);
            const bool inc = (!dec) && (Tylm1 > Txk);
            k += inc ? 1 : (dec ? -1 : 0);
        }

        const int m = n - k;
        const float Txk   = __fmaf_rn((float)k, px, Ax);
        const float Txkm1 = (k > 0) ? __fmaf_rn((float)(k - 1), px, Ax) : -INFp;
        const float Tyl   = __fmaf_rn((float)m, py, Ay);
        const float Tylm1 = (m > 0) ? __fmaf_rn((float)(m - 1), py, Ay) : -INFp;

        const float Tn   = fminf(Txk, Tyl);                 // event ending segment n
        const float prev = fmaxf(te, fmaxf(Txkm1, Tylm1));  // event starting it
        const float dt   = __fadd_rn(fminf(Tn, tex), -fminf(prev, tex));
        const bool active = alive0 && (prev < tex_m_eps);
        float w = __fmul_rn(fmaxf(0.0f, dt), wscale);
        w = active ? w : 0.0f;

        const int ii = min(95, max(0, i0 + ((si > 0) ? k : -k)));
        const int jj = min(95, max(0, j0 + ((sj > 0) ? m : -m)));
        int2 e;
        e.x = (ii * NH + jj) << 8;             // BYTE offset into vol (256B rows)
        e.y = __float_as_int(w);
        myRow[n] = e;

        cnt += (int)__popcll(__ballot(active));
    }
    // cap is WAVE-UNIFORM (popc of ballots) -> SGPRs, no LDS, no barrier
    // (sEnt[wid] is wave-private; intra-wave LDS ordering via lgkmcnt).
    const int cap = min((cnt + 15) & ~15, CNTMAX);

    // consume the prefetch results here: forces the loads to exist, and the
    // vmcnt wait lands AFTER the trace -> latency fully overlapped.
    asm volatile("" :: "v"(wA.x), "v"(wA.y), "v"(wA.z), "v"(wA.w),
                       "v"(wB.x), "v"(wB.y), "v"(wB.z), "v"(wB.w));

    // ---------------- gather: quad-row (R10 structure, validated) ----------
    // Lane L: row-in-quad r=L>>4, 16B chunk sub=L&15. One dwordx4 per 4 entries
    // fetches four 256B vol rows.
    const int r   = lane >> 4;
    const int sub = lane & 15;
    const int subOff = sub << 4;

    const int2* __restrict__ eRow = &sEnt[wid][r];   // entry n+r at [n]
    const char* __restrict__ vb   = (const char*)vol;

    float4 acc[4] = {{0,0,0,0}, {0,0,0,0}, {0,0,0,0}, {0,0,0,0}};
    for (int n = 0; n < cap; n += 16) {
        const int2 e0 = eRow[n];        // 4-address LDS broadcast (conflict-free)
        const int2 e1 = eRow[n + 4];
        const int2 e2 = eRow[n + 8];
        const int2 e3 = eRow[n + 12];
        const float4 v0 = *(const float4*)(vb + (e0.x + subOff));  // 4 rows/instr
        const float4 v1 = *(const float4*)(vb + (e1.x + subOff));
        const float4 v2 = *(const float4*)(vb + (e2.x + subOff));
        const float4 v3 = *(const float4*)(vb + (e3.x + subOff));
        const float w0 = __int_as_float(e0.y);
        const float w1 = __int_as_float(e1.y);
        const float w2 = __int_as_float(e2.y);
        const float w3 = __int_as_float(e3.y);
        acc[0].x = fmaf(w0, v0.x, acc[0].x); acc[0].y = fmaf(w0, v0.y, acc[0].y);
        acc[0].z = fmaf(w0, v0.z, acc[0].z); acc[0].w = fmaf(w0, v0.w, acc[0].w);
        acc[1].x = fmaf(w1, v1.x, acc[1].x); acc[1].y = fmaf(w1, v1.y, acc[1].y);
        acc[1].z = fmaf(w1, v1.z, acc[1].z); acc[1].w = fmaf(w1, v1.w, acc[1].w);
        acc[2].x = fmaf(w2, v2.x, acc[2].x); acc[2].y = fmaf(w2, v2.y, acc[2].y);
        acc[2].z = fmaf(w2, v2.z, acc[2].z); acc[2].w = fmaf(w2, v2.w, acc[2].w);
        acc[3].x = fmaf(w3, v3.x, acc[3].x); acc[3].y = fmaf(w3, v3.y, acc[3].y);
        acc[3].z = fmaf(w3, v3.z, acc[3].z); acc[3].w = fmaf(w3, v3.w, acc[3].w);
    }

    float sx = (acc[0].x + acc[1].x) + (acc[2].x + acc[3].x);
    float sy = (acc[0].y + acc[1].y) + (acc[2].y + acc[3].y);
    float sz = (acc[0].z + acc[1].z) + (acc[2].z + acc[3].z);
    float sw = (acc[0].w + acc[1].w) + (acc[2].w + acc[3].w);

    // reduce across the 4 row groups: lanes {sub, 16+sub, 32+sub, 48+sub}
    sx += __shfl_xor(sx, 16, 64);  sy += __shfl_xor(sy, 16, 64);
    sz += __shfl_xor(sz, 16, 64);  sw += __shfl_xor(sw, 16, 64);
    sx += __shfl_xor(sx, 32, 64);  sy += __shfl_xor(sy, 32, 64);
    sz += __shfl_xor(sz, 32, 64);  sw += __shfl_xor(sw, 32, 64);

    if (lane < 16) {
        float4 res; res.x = sx; res.y = sy; res.z = sz; res.w = sw;
        *(float4*)(out + (u * NA + a) * NV + (sub << 2)) = res;  // 256B coalesced
    }
}

extern "C" void kernel_launch(void* const* d_in, const int* in_sizes, int n_in,
                              void* d_out, int out_size, void* d_ws, size_t ws_size,
                              hipStream_t stream) {
    const float* vol = (const float*)d_in[0];
    float* out = (float*)d_out;
    hipLaunchKernelGGL(siddon_fused, dim3(NBLK), dim3(512), 0, stream, vol, out);
}